// Round 1
// baseline (487.452 us; speedup 1.0000x reference)
//
#include <hip/hip_runtime.h>
#include <cstddef>

#define BATCH 16384
#define IN_F  4096
#define OUT_F 4096
#define ROWS_PER_BLOCK 64

// Keys cubic convolution, a = -0.75 (torch bicubic), align_corners=True.
__device__ __forceinline__ float cub_inner(float s) {
    // ((a+2)s - (a+3)) s^2 + 1
    return (1.25f * s - 2.25f) * s * s + 1.0f;
}
__device__ __forceinline__ float cub_outer(float s) {
    // ((a s - 5a)s + 8a)s - 4a
    return ((-0.75f * s + 3.75f) * s - 6.0f) * s + 3.0f;
}

// Row i of the (4096, 4) cubic interpolation matrix (border-replicated).
__device__ __forceinline__ void cubic_row(int i, float& a0, float& a1, float& a2, float& a3) {
    const float inv = 3.0f / 4095.0f;
    const float xi = (float)i * inv;
    const float x0 = floorf(xi);
    const float t  = xi - x0;
    const int   c  = (int)x0;
    const float w0 = cub_outer(t + 1.0f);
    const float w1 = cub_inner(t);
    const float w2 = cub_inner(1.0f - t);
    const float w3 = cub_outer(2.0f - t);
    // scatter taps (c-1..c+2) with index clamp to [0,3]
    if (c == 0)      { a0 = w0 + w1; a1 = w2;   a2 = w3;   a3 = 0.0f; }
    else if (c == 1) { a0 = w0;      a1 = w1;   a2 = w2;   a3 = w3; }
    else if (c == 2) { a0 = 0.0f;    a1 = w0;   a2 = w1;   a3 = w2 + w3; }
    else             { a0 = 0.0f;    a1 = 0.0f; a2 = w0;   a3 = w1 + w2 + w3; }
}

// Kernel 1: t[b][w] = sum_i x[b][i] * A_in[i][w].  One block per batch row.
__global__ __launch_bounds__(256) void k_project(const float* __restrict__ x,
                                                 float* __restrict__ tproj) {
    const int b   = blockIdx.x;
    const int tid = threadIdx.x;
    const float4* xrow = (const float4*)(x + (size_t)b * IN_F);
    float acc0 = 0.f, acc1 = 0.f, acc2 = 0.f, acc3 = 0.f;
#pragma unroll
    for (int k = 0; k < 4; ++k) {
        const int v4 = k * 256 + tid;          // float4 index within the row
        const float4 xv = xrow[v4];
        const int i = v4 * 4;
        float a0, a1, a2, a3;
        cubic_row(i + 0, a0, a1, a2, a3);
        acc0 += a0 * xv.x; acc1 += a1 * xv.x; acc2 += a2 * xv.x; acc3 += a3 * xv.x;
        cubic_row(i + 1, a0, a1, a2, a3);
        acc0 += a0 * xv.y; acc1 += a1 * xv.y; acc2 += a2 * xv.y; acc3 += a3 * xv.y;
        cubic_row(i + 2, a0, a1, a2, a3);
        acc0 += a0 * xv.z; acc1 += a1 * xv.z; acc2 += a2 * xv.z; acc3 += a3 * xv.z;
        cubic_row(i + 3, a0, a1, a2, a3);
        acc0 += a0 * xv.w; acc1 += a1 * xv.w; acc2 += a2 * xv.w; acc3 += a3 * xv.w;
    }
    // wave(64) shuffle reduce
#pragma unroll
    for (int off = 32; off > 0; off >>= 1) {
        acc0 += __shfl_down(acc0, off);
        acc1 += __shfl_down(acc1, off);
        acc2 += __shfl_down(acc2, off);
        acc3 += __shfl_down(acc3, off);
    }
    __shared__ float lds[4][4];
    const int wid = tid >> 6;
    if ((tid & 63) == 0) {
        lds[wid][0] = acc0; lds[wid][1] = acc1; lds[wid][2] = acc2; lds[wid][3] = acc3;
    }
    __syncthreads();
    if (tid < 4) {
        tproj[(size_t)b * 4 + tid] = lds[0][tid] + lds[1][tid] + lds[2][tid] + lds[3][tid];
    }
}

// Kernel 2: y[b][o] = sum_w (sum_h A_out[o][h] CP[h][w]) * t[b][w] + bias[o].
// Each thread owns 4 consecutive outputs (float4 store), loops over 64 rows
// so the per-output weight computation is amortized.
__global__ __launch_bounds__(256) void k_expand(const float* __restrict__ tproj,
                                                const float* __restrict__ cp,
                                                const float* __restrict__ bcp,
                                                float* __restrict__ y) {
    const int oq = blockIdx.x * 256 + threadIdx.x;   // output quad index, 0..1023
    const int o0 = oq * 4;
    float cpr[16];
#pragma unroll
    for (int k = 0; k < 16; ++k) cpr[k] = cp[k];     // CP_H x CP_W row-major
    const float b0 = bcp[0], b1 = bcp[1], b2 = bcp[2], b3 = bcp[3];

    float we[4][4];
    float bs[4];
#pragma unroll
    for (int j = 0; j < 4; ++j) {
        const int o = o0 + j;
        float h0, h1, h2, h3;
        cubic_row(o, h0, h1, h2, h3);
#pragma unroll
        for (int w = 0; w < 4; ++w)
            we[j][w] = h0 * cpr[w] + h1 * cpr[4 + w] + h2 * cpr[8 + w] + h3 * cpr[12 + w];
        // linearly interpolated bias (align_corners=True, 4 control points)
        const float xb = (float)o * (3.0f / 4095.0f);
        const float lo = floorf(xb);
        const float tb = xb - lo;
        const int   l  = (int)lo;
        const float blo = (l == 0) ? b0 : (l == 1) ? b1 : (l == 2) ? b2 : b3;
        const float bhi = (l >= 2) ? b3 : (l == 1) ? b2 : b1;
        bs[j] = (1.0f - tb) * blo + tb * bhi;
    }

    const int r0 = blockIdx.y * ROWS_PER_BLOCK;
#pragma unroll 4
    for (int r = 0; r < ROWS_PER_BLOCK; ++r) {
        const int b = r0 + r;
        const float4 tv = *(const float4*)(tproj + (size_t)b * 4);
        float4 out;
        out.x = bs[0] + we[0][0]*tv.x + we[0][1]*tv.y + we[0][2]*tv.z + we[0][3]*tv.w;
        out.y = bs[1] + we[1][0]*tv.x + we[1][1]*tv.y + we[1][2]*tv.z + we[1][3]*tv.w;
        out.z = bs[2] + we[2][0]*tv.x + we[2][1]*tv.y + we[2][2]*tv.z + we[2][3]*tv.w;
        out.w = bs[3] + we[3][0]*tv.x + we[3][1]*tv.y + we[3][2]*tv.z + we[3][3]*tv.w;
        *(float4*)(y + (size_t)b * OUT_F + o0) = out;
    }
}

extern "C" void kernel_launch(void* const* d_in, const int* in_sizes, int n_in,
                              void* d_out, int out_size, void* d_ws, size_t ws_size,
                              hipStream_t stream) {
    const float* x   = (const float*)d_in[0];   // (16384, 4096) f32
    const float* cp  = (const float*)d_in[1];   // (4, 4) f32
    const float* bcp = (const float*)d_in[2];   // (4,) f32
    float* y = (float*)d_out;                   // (16384, 4096) f32
    float* tproj = (float*)d_ws;                // 16384*4 f32 = 256 KB scratch

    k_project<<<dim3(BATCH), dim3(256), 0, stream>>>(x, tproj);
    dim3 g2(OUT_F / (256 * 4), BATCH / ROWS_PER_BLOCK);  // (4, 256)
    k_expand<<<g2, dim3(256), 0, stream>>>(tproj, cp, bcp, y);
}